// Round 1
// baseline (260.025 us; speedup 1.0000x reference)
//
#include <hip/hip_runtime.h>

typedef unsigned short u16;
typedef __bf16 bf16x8 __attribute__((ext_vector_type(8)));
typedef float f32x4 __attribute__((ext_vector_type(4)));
typedef unsigned short u16x8 __attribute__((ext_vector_type(8)));

#define T_SEQ 4096
#define DIN 1024
#define DH 64

static __device__ __forceinline__ u16 f2bf(float f) {
    return __builtin_bit_cast(u16, (__bf16)f);
}

// ---------------------------------------------------------------------------
// Kernel 0: W [1024][64] fp32  ->  Wt [3][64][1024] bf16 (transposed)
// ---------------------------------------------------------------------------
__global__ __launch_bounds__(256) void transpose_w(
    const float* __restrict__ Wq, const float* __restrict__ Wk,
    const float* __restrict__ Wv, u16* __restrict__ Wt)
{
    int idx = blockIdx.x * 256 + threadIdx.x;   // 12288 threads total
    int m   = idx >> 12;                        // 0..2
    int rem = idx & 4095;
    int e   = rem & 63;                         // output row (head dim)
    int k0  = (rem >> 6) << 4;                  // 16-wide k chunk
    const float* W = (m == 0) ? Wq : (m == 1 ? Wk : Wv);
    u16x8 v0, v1;
#pragma unroll
    for (int i = 0; i < 8; i++) v0[i] = f2bf(W[(size_t)(k0 + i) * DH + e]);
#pragma unroll
    for (int i = 0; i < 8; i++) v1[i] = f2bf(W[(size_t)(k0 + 8 + i) * DH + e]);
    u16* dst = Wt + ((size_t)m * DH + e) * DIN + k0;
    *(u16x8*)(dst)     = v0;
    *(u16x8*)(dst + 8) = v1;
}

// ---------------------------------------------------------------------------
// Kernel 1: QKV projection.  x [B*T][1024] fp32 @ Wt -> Qb/Kb [B][T][64] bf16,
//           Vt [B][64][T] bf16 (transposed via LDS).
// Block: 256 thr (4 waves), 64 rows of x. Wave w: rows r0+w*16..+16, all 192 cols.
// ---------------------------------------------------------------------------
__global__ __launch_bounds__(256) void qkv_proj(
    const float* __restrict__ x, const u16* __restrict__ Wt,
    u16* __restrict__ Qb, u16* __restrict__ Kb, u16* __restrict__ Vtg)
{
    const int r0   = blockIdx.x * 64;
    const int w    = threadIdx.x >> 6;
    const int lane = threadIdx.x & 63;
    const int lg   = lane >> 4, li = lane & 15;

    const float* xp = x + (size_t)(r0 + w * 16 + li) * DIN + lg * 8;
    const u16*   wp = Wt + (size_t)li * DIN + lg * 8;

    f32x4 acc[3][4];
#pragma unroll
    for (int m = 0; m < 3; m++)
#pragma unroll
        for (int t = 0; t < 4; t++) acc[m][t] = (f32x4){0.f, 0.f, 0.f, 0.f};

    // ---- software-pipelined k loop (1-deep prefetch) ----
    bf16x8 aF, wF[12];
    {
        float4 a = *(const float4*)(xp);
        float4 b = *(const float4*)(xp + 4);
        aF[0] = (__bf16)a.x; aF[1] = (__bf16)a.y; aF[2] = (__bf16)a.z; aF[3] = (__bf16)a.w;
        aF[4] = (__bf16)b.x; aF[5] = (__bf16)b.y; aF[6] = (__bf16)b.z; aF[7] = (__bf16)b.w;
    }
#pragma unroll
    for (int m = 0; m < 3; m++)
#pragma unroll
        for (int t = 0; t < 4; t++)
            wF[m * 4 + t] = *(const bf16x8*)(wp + (size_t)(m * 64 + t * 16) * DIN);

    for (int k0 = 0; k0 < DIN; k0 += 32) {
        bf16x8 aN, wN[12];
        if (k0 + 32 < DIN) {
            float4 a = *(const float4*)(xp + k0 + 32);
            float4 b = *(const float4*)(xp + k0 + 36);
            aN[0] = (__bf16)a.x; aN[1] = (__bf16)a.y; aN[2] = (__bf16)a.z; aN[3] = (__bf16)a.w;
            aN[4] = (__bf16)b.x; aN[5] = (__bf16)b.y; aN[6] = (__bf16)b.z; aN[7] = (__bf16)b.w;
#pragma unroll
            for (int m = 0; m < 3; m++)
#pragma unroll
                for (int t = 0; t < 4; t++)
                    wN[m * 4 + t] = *(const bf16x8*)(wp + (size_t)(m * 64 + t * 16) * DIN + k0 + 32);
        }
#pragma unroll
        for (int m = 0; m < 3; m++)
#pragma unroll
            for (int t = 0; t < 4; t++)
                acc[m][t] = __builtin_amdgcn_mfma_f32_16x16x32_bf16(aF, wF[m * 4 + t], acc[m][t], 0, 0, 0);
        aF = aN;
#pragma unroll
        for (int i = 0; i < 12; i++) wF[i] = wN[i];
    }

    // ---- epilogue: Q, K row-major bf16 ----
    // C layout: row = lg*4+r (local), col = t*16+li
#pragma unroll
    for (int t = 0; t < 4; t++)
#pragma unroll
        for (int r = 0; r < 4; r++) {
            size_t row = (size_t)(r0 + w * 16 + lg * 4 + r);
            Qb[row * DH + t * 16 + li] = f2bf(acc[0][t][r]);
            Kb[row * DH + t * 16 + li] = f2bf(acc[1][t][r]);
        }

    // ---- V: transpose through LDS -> Vt [B][64][T] ----
    __shared__ u16 vt_lds[64][72];   // padded stride: conflict-free
#pragma unroll
    for (int t = 0; t < 4; t++)
#pragma unroll
        for (int r = 0; r < 4; r++)
            vt_lds[w * 16 + lg * 4 + r][t * 16 + li] = f2bf(acc[2][t][r]);
    __syncthreads();

    const int bb    = r0 >> 12;        // batch
    const int tbase = r0 & 4095;       // t offset within batch
    const int e  = threadIdx.x & 63;   // within-wave lane == head-dim col
    const int tc = threadIdx.x >> 6;   // 16-row chunk
    u16x8 o0, o1;
#pragma unroll
    for (int i = 0; i < 8; i++) o0[i] = vt_lds[tc * 16 + i][e];
#pragma unroll
    for (int i = 0; i < 8; i++) o1[i] = vt_lds[tc * 16 + 8 + i][e];
    u16* dst = Vtg + ((size_t)bb * DH + e) * T_SEQ + tbase + tc * 16;
    *(u16x8*)(dst)     = o0;
    *(u16x8*)(dst + 8) = o1;
}

// ---------------------------------------------------------------------------
// Kernel 2: causal flash attention.
// Grid: 256 blocks = B(4) x 64 q-tiles of 64 rows. 4 waves; wave w owns 16 q rows.
// ---------------------------------------------------------------------------
__global__ __launch_bounds__(256) void flash_attn(
    const u16* __restrict__ Qb, const u16* __restrict__ Kb,
    const u16* __restrict__ Vtg, float* __restrict__ out)
{
    const int b    = blockIdx.x >> 6;
    const int qt   = blockIdx.x & 63;
    const int w    = threadIdx.x >> 6;
    const int lane = threadIdx.x & 63;
    const int lg   = lane >> 4, li = lane & 15;

    const int q0 = qt * 64 + w * 16;  // wave's first q row (within batch)

    const u16* Qp = Qb + ((size_t)b * T_SEQ + q0) * DH;
    const u16* Kp = Kb + (size_t)b * T_SEQ * DH;
    const u16* Vp = Vtg + (size_t)b * DH * T_SEQ;

    // Q A-frags (row = li, k = lg*8+j, d-slices 0/32) — loaded once
    bf16x8 qf0 = *(const bf16x8*)(Qp + (size_t)li * DH + lg * 8);
    bf16x8 qf1 = *(const bf16x8*)(Qp + (size_t)li * DH + 32 + lg * 8);

    f32x4 o[4];
#pragma unroll
    for (int t = 0; t < 4; t++) o[t] = (f32x4){0.f, 0.f, 0.f, 0.f};
    float m[4], l[4];
#pragma unroll
    for (int r = 0; r < 4; r++) { m[r] = -1e30f; l[r] = 0.f; }

    __shared__ u16 p_lds[4][16][72];      // wave-private, padded
    u16 (*pl)[72] = p_lds[w];

    const float c_sc = 0.125f * 1.44269504f;  // 1/sqrt(64) * log2(e)

    const int ntiles = qt + 1;
    for (int kt = 0; kt < ntiles; ++kt) {
        const int kv0 = kt * 64;

        // ---- S = Q K^T  (4 k-subtiles x 2 d-slices) ----
        f32x4 s[4];
#pragma unroll
        for (int t = 0; t < 4; t++) s[t] = (f32x4){0.f, 0.f, 0.f, 0.f};
#pragma unroll
        for (int t = 0; t < 4; t++) {
            const u16* kp = Kp + (size_t)(kv0 + t * 16 + li) * DH + lg * 8;
            bf16x8 kb0 = *(const bf16x8*)(kp);
            bf16x8 kb1 = *(const bf16x8*)(kp + 32);
            s[t] = __builtin_amdgcn_mfma_f32_16x16x32_bf16(qf0, kb0, s[t], 0, 0, 0);
            s[t] = __builtin_amdgcn_mfma_f32_16x16x32_bf16(qf1, kb1, s[t], 0, 0, 0);
        }

        // ---- causal mask on the diagonal tile ----
        if (kt == qt) {
#pragma unroll
            for (int t = 0; t < 4; t++)
#pragma unroll
                for (int r = 0; r < 4; r++) {
                    int qrow = w * 16 + lg * 4 + r;
                    int kcol = t * 16 + li;
                    if (kcol > qrow) s[t][r] = -1e30f;
                }
        }

        // ---- online softmax ----
        float pm[4];
#pragma unroll
        for (int r = 0; r < 4; r++) {
            float v = fmaxf(fmaxf(s[0][r], s[1][r]), fmaxf(s[2][r], s[3][r]));
            v = fmaxf(v, __shfl_xor(v, 1));
            v = fmaxf(v, __shfl_xor(v, 2));
            v = fmaxf(v, __shfl_xor(v, 4));
            v = fmaxf(v, __shfl_xor(v, 8));
            pm[r] = v;
        }
#pragma unroll
        for (int r = 0; r < 4; r++) {
            float mn    = fmaxf(m[r], pm[r]);
            float alpha = __builtin_amdgcn_exp2f((m[r] - mn) * c_sc);
            m[r] = mn;
            l[r] *= alpha;
            o[0][r] *= alpha; o[1][r] *= alpha; o[2][r] *= alpha; o[3][r] *= alpha;
        }
        float rs[4] = {0.f, 0.f, 0.f, 0.f};
#pragma unroll
        for (int t = 0; t < 4; t++)
#pragma unroll
            for (int r = 0; r < 4; r++) {
                float p = __builtin_amdgcn_exp2f((s[t][r] - m[r]) * c_sc);
                s[t][r] = p;
                rs[r] += p;
            }
#pragma unroll
        for (int r = 0; r < 4; r++) {
            float v = rs[r];
            v += __shfl_xor(v, 1);
            v += __shfl_xor(v, 2);
            v += __shfl_xor(v, 4);
            v += __shfl_xor(v, 8);
            l[r] += v;
        }

        // ---- P -> LDS (C layout) -> A-frags ----
#pragma unroll
        for (int t = 0; t < 4; t++)
#pragma unroll
            for (int r = 0; r < 4; r++)
                pl[lg * 4 + r][t * 16 + li] = f2bf(s[t][r]);

        bf16x8 pa0 = *(const bf16x8*)(&pl[li][lg * 8]);
        bf16x8 pa1 = *(const bf16x8*)(&pl[li][32 + lg * 8]);

        // ---- O += P V  (4 e-subtiles x 2 k-slices) ----
#pragma unroll
        for (int t = 0; t < 4; t++) {
            const u16* vp = Vp + (size_t)(t * 16 + li) * T_SEQ + kv0 + lg * 8;
            bf16x8 vb0 = *(const bf16x8*)(vp);
            bf16x8 vb1 = *(const bf16x8*)(vp + 32);
            o[t] = __builtin_amdgcn_mfma_f32_16x16x32_bf16(pa0, vb0, o[t], 0, 0, 0);
            o[t] = __builtin_amdgcn_mfma_f32_16x16x32_bf16(pa1, vb1, o[t], 0, 0, 0);
        }
    }

    // ---- epilogue ----
    float* op = out + ((size_t)b * T_SEQ + q0) * DH;
#pragma unroll
    for (int r = 0; r < 4; r++) {
        float inv = 1.f / l[r];
#pragma unroll
        for (int t = 0; t < 4; t++)
            op[(size_t)(lg * 4 + r) * DH + t * 16 + li] = o[t][r] * inv;
    }
}

// ---------------------------------------------------------------------------
extern "C" void kernel_launch(void* const* d_in, const int* in_sizes, int n_in,
                              void* d_out, int out_size, void* d_ws, size_t ws_size,
                              hipStream_t stream) {
    const float* x  = (const float*)d_in[0];
    const float* Wq = (const float*)d_in[1];
    const float* Wk = (const float*)d_in[2];
    const float* Wv = (const float*)d_in[3];
    float* out = (float*)d_out;

    char* ws = (char*)d_ws;
    u16* Wt  = (u16*)(ws);                 //   393,216 B
    u16* Qb  = (u16*)(ws + 393216);        // 2,097,152 B
    u16* Kb  = (u16*)(ws + 2490368);       // 2,097,152 B
    u16* Vt  = (u16*)(ws + 4587520);       // 2,097,152 B  (total ~6.7 MB)

    hipLaunchKernelGGL(transpose_w, dim3(48),  dim3(256), 0, stream, Wq, Wk, Wv, Wt);
    hipLaunchKernelGGL(qkv_proj,    dim3(256), dim3(256), 0, stream, x, Wt, Qb, Kb, Vt);
    hipLaunchKernelGGL(flash_attn,  dim3(256), dim3(256), 0, stream, Qb, Kb, Vt, out);
}

// Round 2
// 238.694 us; speedup vs baseline: 1.0894x; 1.0894x over previous
//
#include <hip/hip_runtime.h>

typedef unsigned short u16;
typedef __bf16 bf16x8 __attribute__((ext_vector_type(8)));
typedef float f32x4 __attribute__((ext_vector_type(4)));
typedef unsigned short u16x4 __attribute__((ext_vector_type(4)));
typedef unsigned short u16x8 __attribute__((ext_vector_type(8)));

#define T_SEQ 4096
#define DIN 1024
#define DH 64
#define NSPLIT 4

static __device__ __forceinline__ u16 f2bf(float f) {
    return __builtin_bit_cast(u16, (__bf16)f);
}

// ---------------------------------------------------------------------------
// Kernel 0: W [1024][64] fp32  ->  Wt [3][64][1024] bf16 (transposed)
// ---------------------------------------------------------------------------
__global__ __launch_bounds__(256) void transpose_w(
    const float* __restrict__ Wq, const float* __restrict__ Wk,
    const float* __restrict__ Wv, u16* __restrict__ Wt)
{
    int idx = blockIdx.x * 256 + threadIdx.x;   // 12288 threads total
    int m   = idx >> 12;                        // 0..2
    int rem = idx & 4095;
    int e   = rem & 63;                         // output row (head dim)
    int k0  = (rem >> 6) << 4;                  // 16-wide k chunk
    const float* W = (m == 0) ? Wq : (m == 1 ? Wk : Wv);
    u16x8 v0, v1;
#pragma unroll
    for (int i = 0; i < 8; i++) v0[i] = f2bf(W[(size_t)(k0 + i) * DH + e]);
#pragma unroll
    for (int i = 0; i < 8; i++) v1[i] = f2bf(W[(size_t)(k0 + 8 + i) * DH + e]);
    u16* dst = Wt + ((size_t)m * DH + e) * DIN + k0;
    *(u16x8*)(dst)     = v0;
    *(u16x8*)(dst + 8) = v1;
}

// ---------------------------------------------------------------------------
// Kernel 1: QKV projection, split-K across the 4 waves of a block.
// Block: 16 token rows; wave w handles k in [w*256, w*256+256). LDS combine.
// Grid: 1024 blocks -> 4096 waves (vs 1024 before) for latency hiding.
// ---------------------------------------------------------------------------
__global__ __launch_bounds__(256) void qkv_proj(
    const float* __restrict__ x, const u16* __restrict__ Wt,
    u16* __restrict__ Qb, u16* __restrict__ Kb, u16* __restrict__ Vtg)
{
    const int r0   = blockIdx.x * 16;
    const int w    = threadIdx.x >> 6;
    const int lane = threadIdx.x & 63;
    const int lg   = lane >> 4, li = lane & 15;
    const int kb   = w * 256;

    const float* xp = x + (size_t)(r0 + li) * DIN + kb + lg * 8;
    const u16*   wp = Wt + (size_t)li * DIN + kb + lg * 8;

    f32x4 acc[3][4];
#pragma unroll
    for (int m = 0; m < 3; m++)
#pragma unroll
        for (int t = 0; t < 4; t++) acc[m][t] = (f32x4){0.f, 0.f, 0.f, 0.f};

    // 1-deep prefetch on the x (HBM) stream; weights are L2-hot, load in-loop.
    bf16x8 aF;
    {
        float4 a = *(const float4*)(xp);
        float4 b = *(const float4*)(xp + 4);
        aF[0] = (__bf16)a.x; aF[1] = (__bf16)a.y; aF[2] = (__bf16)a.z; aF[3] = (__bf16)a.w;
        aF[4] = (__bf16)b.x; aF[5] = (__bf16)b.y; aF[6] = (__bf16)b.z; aF[7] = (__bf16)b.w;
    }
#pragma unroll
    for (int k0 = 0; k0 < 256; k0 += 32) {
        bf16x8 aN;
        if (k0 + 32 < 256) {
            float4 a = *(const float4*)(xp + k0 + 32);
            float4 b = *(const float4*)(xp + k0 + 36);
            aN[0] = (__bf16)a.x; aN[1] = (__bf16)a.y; aN[2] = (__bf16)a.z; aN[3] = (__bf16)a.w;
            aN[4] = (__bf16)b.x; aN[5] = (__bf16)b.y; aN[6] = (__bf16)b.z; aN[7] = (__bf16)b.w;
        }
#pragma unroll
        for (int m = 0; m < 3; m++)
#pragma unroll
            for (int t = 0; t < 4; t++) {
                bf16x8 wv = *(const bf16x8*)(wp + (size_t)(m * 64 + t * 16) * DIN + k0);
                acc[m][t] = __builtin_amdgcn_mfma_f32_16x16x32_bf16(aF, wv, acc[m][t], 0, 0, 0);
            }
        aF = aN;
    }

    // ---- combine the 4 k-slices via LDS (stride 196: 2-way banks, free) ----
    __shared__ __align__(16) float pl[4][16][196];
#pragma unroll
    for (int m = 0; m < 3; m++)
#pragma unroll
        for (int t = 0; t < 4; t++)
#pragma unroll
            for (int r = 0; r < 4; r++)
                pl[w][lg * 4 + r][m * 64 + t * 16 + li] = acc[m][t][r];
    __syncthreads();

    // Q, K: row-major bf16, coalesced
    {
        const int row = threadIdx.x >> 4;          // 0..15
        const int c0  = (threadIdx.x & 15) * 4;    // 0..60
#pragma unroll
        for (int m = 0; m < 2; m++) {
            float4 s = {0.f, 0.f, 0.f, 0.f};
#pragma unroll
            for (int w2 = 0; w2 < 4; w2++) {
                float4 v = *(const float4*)&pl[w2][row][m * 64 + c0];
                s.x += v.x; s.y += v.y; s.z += v.z; s.w += v.w;
            }
            u16x4 ov;
            ov[0] = f2bf(s.x); ov[1] = f2bf(s.y); ov[2] = f2bf(s.z); ov[3] = f2bf(s.w);
            u16* dst = (m ? Kb : Qb) + (size_t)(r0 + row) * DH + c0;
            *(u16x4*)dst = ov;
        }
    }
    // V: transposed -> Vt [B][64][T]
    {
        const int e     = threadIdx.x & 63;
        const int rg    = threadIdx.x >> 6;        // 0..3 (4 rows each)
        const int bb    = r0 >> 12;
        const int tbase = r0 & 4095;
        u16x4 ov;
#pragma unroll
        for (int j = 0; j < 4; j++) {
            float s = 0.f;
#pragma unroll
            for (int w2 = 0; w2 < 4; w2++) s += pl[w2][rg * 4 + j][128 + e];
            ov[j] = f2bf(s);
        }
        *(u16x4*)(Vtg + ((size_t)bb * DH + e) * T_SEQ + tbase + rg * 4) = ov;
    }
}

// ---------------------------------------------------------------------------
// Kernel 2: causal flash attention, split-KV (4 splits per q-tile).
// Grid: 1024 blocks = B(4) x 64 q-tiles x 4 splits; 4 waves of 16 q rows.
// Split s does kv-tiles kt = s, s+4, ... <= qt; writes unnormalized partials.
// ---------------------------------------------------------------------------
__global__ __launch_bounds__(256) void flash_attn(
    const u16* __restrict__ Qb, const u16* __restrict__ Kb,
    const u16* __restrict__ Vtg, float* __restrict__ opart,
    float* __restrict__ mpart, float* __restrict__ lpart)
{
    const int bid  = blockIdx.x;
    const int sp   = bid & (NSPLIT - 1);
    const int qt   = (bid >> 2) & 63;
    const int b    = bid >> 8;
    const int w    = threadIdx.x >> 6;
    const int lane = threadIdx.x & 63;
    const int lg   = lane >> 4, li = lane & 15;

    const int q0 = qt * 64 + w * 16;

    const u16* Qp = Qb + ((size_t)b * T_SEQ + q0) * DH;
    const u16* Kp = Kb + (size_t)b * T_SEQ * DH;
    const u16* Vp = Vtg + (size_t)b * DH * T_SEQ;

    bf16x8 qf0 = *(const bf16x8*)(Qp + (size_t)li * DH + lg * 8);
    bf16x8 qf1 = *(const bf16x8*)(Qp + (size_t)li * DH + 32 + lg * 8);

    f32x4 o[4];
#pragma unroll
    for (int t = 0; t < 4; t++) o[t] = (f32x4){0.f, 0.f, 0.f, 0.f};
    float m[4], l[4];
#pragma unroll
    for (int r = 0; r < 4; r++) { m[r] = -1e30f; l[r] = 0.f; }

    __shared__ u16 p_lds[4][16][72];
    u16 (*pl)[72] = p_lds[w];

    const float c_sc = 0.125f * 1.44269504f;  // 1/sqrt(64) * log2(e)

    for (int kt = sp; kt <= qt; kt += NSPLIT) {
        const int kv0 = kt * 64;

        f32x4 s[4];
#pragma unroll
        for (int t = 0; t < 4; t++) s[t] = (f32x4){0.f, 0.f, 0.f, 0.f};
#pragma unroll
        for (int t = 0; t < 4; t++) {
            const u16* kp = Kp + (size_t)(kv0 + t * 16 + li) * DH + lg * 8;
            bf16x8 kb0 = *(const bf16x8*)(kp);
            bf16x8 kb1 = *(const bf16x8*)(kp + 32);
            s[t] = __builtin_amdgcn_mfma_f32_16x16x32_bf16(qf0, kb0, s[t], 0, 0, 0);
            s[t] = __builtin_amdgcn_mfma_f32_16x16x32_bf16(qf1, kb1, s[t], 0, 0, 0);
        }

        if (kt == qt) {
#pragma unroll
            for (int t = 0; t < 4; t++)
#pragma unroll
                for (int r = 0; r < 4; r++) {
                    int qrow = w * 16 + lg * 4 + r;
                    int kcol = t * 16 + li;
                    if (kcol > qrow) s[t][r] = -1e30f;
                }
        }

        float pm[4];
#pragma unroll
        for (int r = 0; r < 4; r++) {
            float v = fmaxf(fmaxf(s[0][r], s[1][r]), fmaxf(s[2][r], s[3][r]));
            v = fmaxf(v, __shfl_xor(v, 1));
            v = fmaxf(v, __shfl_xor(v, 2));
            v = fmaxf(v, __shfl_xor(v, 4));
            v = fmaxf(v, __shfl_xor(v, 8));
            pm[r] = v;
        }
#pragma unroll
        for (int r = 0; r < 4; r++) {
            float mn    = fmaxf(m[r], pm[r]);
            float alpha = __builtin_amdgcn_exp2f((m[r] - mn) * c_sc);
            m[r] = mn;
            l[r] *= alpha;
            o[0][r] *= alpha; o[1][r] *= alpha; o[2][r] *= alpha; o[3][r] *= alpha;
        }
        float rs[4] = {0.f, 0.f, 0.f, 0.f};
#pragma unroll
        for (int t = 0; t < 4; t++)
#pragma unroll
            for (int r = 0; r < 4; r++) {
                float p = __builtin_amdgcn_exp2f((s[t][r] - m[r]) * c_sc);
                s[t][r] = p;
                rs[r] += p;
            }
#pragma unroll
        for (int r = 0; r < 4; r++) {
            float v = rs[r];
            v += __shfl_xor(v, 1);
            v += __shfl_xor(v, 2);
            v += __shfl_xor(v, 4);
            v += __shfl_xor(v, 8);
            l[r] += v;
        }

#pragma unroll
        for (int t = 0; t < 4; t++)
#pragma unroll
            for (int r = 0; r < 4; r++)
                pl[lg * 4 + r][t * 16 + li] = f2bf(s[t][r]);

        bf16x8 pa0 = *(const bf16x8*)(&pl[li][lg * 8]);
        bf16x8 pa1 = *(const bf16x8*)(&pl[li][32 + lg * 8]);

#pragma unroll
        for (int t = 0; t < 4; t++) {
            const u16* vp = Vp + (size_t)(t * 16 + li) * T_SEQ + kv0 + lg * 8;
            bf16x8 vb0 = *(const bf16x8*)(vp);
            bf16x8 vb1 = *(const bf16x8*)(vp + 32);
            o[t] = __builtin_amdgcn_mfma_f32_16x16x32_bf16(pa0, vb0, o[t], 0, 0, 0);
            o[t] = __builtin_amdgcn_mfma_f32_16x16x32_bf16(pa1, vb1, o[t], 0, 0, 0);
        }
    }

    // ---- write unnormalized partials ----
    const int p = (b * 64 + qt) * NSPLIT + sp;
    float* op = opart + (size_t)p * 64 * 64;
#pragma unroll
    for (int t = 0; t < 4; t++)
#pragma unroll
        for (int r = 0; r < 4; r++) {
            int row = w * 16 + lg * 4 + r;
            op[(size_t)row * 64 + t * 16 + li] = o[t][r];
        }
    if (li == 0) {
#pragma unroll
        for (int r = 0; r < 4; r++) {
            int row = w * 16 + lg * 4 + r;
            mpart[(size_t)p * 64 + row] = m[r];
            lpart[(size_t)p * 64 + row] = l[r];
        }
    }
}

// ---------------------------------------------------------------------------
// Kernel 3: merge the 4 KV-splits per (b, q-tile).
// Grid: 1024 blocks (b x qt x 4 row-groups) x 64 threads.
// ---------------------------------------------------------------------------
__global__ __launch_bounds__(64) void attn_combine(
    const float* __restrict__ opart, const float* __restrict__ mpart,
    const float* __restrict__ lpart, float* __restrict__ out)
{
    const int bid = blockIdx.x;
    const int rg  = bid & 3;
    const int qt  = (bid >> 2) & 63;
    const int b   = bid >> 8;
    const int pb  = (b * 64 + qt) * NSPLIT;
    const int row = rg * 16 + (threadIdx.x >> 2);
    const int c0  = (threadIdx.x & 3) * 16;
    const float c_sc = 0.125f * 1.44269504f;

    float mi[NSPLIT], li4[NSPLIT];
#pragma unroll
    for (int s = 0; s < NSPLIT; s++) {
        mi[s]  = mpart[(size_t)(pb + s) * 64 + row];
        li4[s] = lpart[(size_t)(pb + s) * 64 + row];
    }
    float ms = fmaxf(fmaxf(mi[0], mi[1]), fmaxf(mi[2], mi[3]));
    float den = 0.f, wgt[NSPLIT];
#pragma unroll
    for (int s = 0; s < NSPLIT; s++) {
        wgt[s] = exp2f((mi[s] - ms) * c_sc);
        den += wgt[s] * li4[s];
    }
    float4 acc[4];
#pragma unroll
    for (int j = 0; j < 4; j++) acc[j] = (float4){0.f, 0.f, 0.f, 0.f};
#pragma unroll
    for (int s = 0; s < NSPLIT; s++) {
        const float* op = opart + ((size_t)(pb + s) * 64 + row) * 64 + c0;
#pragma unroll
        for (int j = 0; j < 4; j++) {
            float4 v = *(const float4*)(op + j * 4);
            acc[j].x += wgt[s] * v.x; acc[j].y += wgt[s] * v.y;
            acc[j].z += wgt[s] * v.z; acc[j].w += wgt[s] * v.w;
        }
    }
    float inv = 1.f / den;
    float* dst = out + ((size_t)(b * T_SEQ + qt * 64 + row)) * DH + c0;
#pragma unroll
    for (int j = 0; j < 4; j++) {
        float4 v = {acc[j].x * inv, acc[j].y * inv, acc[j].z * inv, acc[j].w * inv};
        *(float4*)(dst + j * 4) = v;
    }
}

// ---------------------------------------------------------------------------
extern "C" void kernel_launch(void* const* d_in, const int* in_sizes, int n_in,
                              void* d_out, int out_size, void* d_ws, size_t ws_size,
                              hipStream_t stream) {
    const float* x  = (const float*)d_in[0];
    const float* Wq = (const float*)d_in[1];
    const float* Wk = (const float*)d_in[2];
    const float* Wv = (const float*)d_in[3];
    float* out = (float*)d_out;

    char* ws = (char*)d_ws;
    u16*   Wt    = (u16*)(ws);                      //    393,216 B
    u16*   Qb    = (u16*)(ws + 393216);             //  2,097,152 B
    u16*   Kb    = (u16*)(ws + 2490368);            //  2,097,152 B
    u16*   Vt    = (u16*)(ws + 4587520);            //  2,097,152 B
    float* opart = (float*)(ws + 6684672);          // 16,777,216 B
    float* mpart = (float*)(ws + 23461888);         //    262,144 B
    float* lpart = (float*)(ws + 23724032);         //    262,144 B  (total ~24 MB)

    hipLaunchKernelGGL(transpose_w,  dim3(48),   dim3(256), 0, stream, Wq, Wk, Wv, Wt);
    hipLaunchKernelGGL(qkv_proj,     dim3(1024), dim3(256), 0, stream, x, Wt, Qb, Kb, Vt);
    hipLaunchKernelGGL(flash_attn,   dim3(1024), dim3(256), 0, stream, Qb, Kb, Vt, opart, mpart, lpart);
    hipLaunchKernelGGL(attn_combine, dim3(1024), dim3(64),  0, stream, opart, mpart, lpart, out);
}